// Round 8
// baseline (141.679 us; speedup 1.0000x reference)
//
#include <hip/hip_runtime.h>
#include <hip/hip_bf16.h>

// MSTAGNN: N=10000, E=160000, HID=64, HEADS=8, D=8, KHOPS=3.
// R8: restore kjb staging (R7 lesson: sequential 20.5MB stream @4-6TB/s beats
// random 41MB ef gather @1.5TB/s even though it's 2x the bytes). hop0 unroll
// 4, hopk unroll 8 for memory-level parallelism. No memsets (deg zeroing in
// qkv, cursor seeded in scan). K-propagation in reference is dead code.

#define HIDC 64
#define MELEMS 512  // HEADS * D * D

__device__ __forceinline__ unsigned bf16rne(float x) {
    unsigned u = __float_as_uint(x);
    return (u + 0x7FFFu + ((u >> 16) & 1u)) >> 16;
}
__device__ __forceinline__ unsigned pack2(float lo, float hi) {
    return bf16rne(lo) | (bf16rne(hi) << 16);
}
__device__ __forceinline__ float bfval(unsigned short v) {
    return __uint_as_float((unsigned)v << 16);
}
__device__ __forceinline__ void acc8(float* acc, float s, uint4 a) {
    acc[0] = fmaf(s, __uint_as_float(a.x << 16), acc[0]);
    acc[1] = fmaf(s, __uint_as_float(a.x & 0xFFFF0000u), acc[1]);
    acc[2] = fmaf(s, __uint_as_float(a.y << 16), acc[2]);
    acc[3] = fmaf(s, __uint_as_float(a.y & 0xFFFF0000u), acc[3]);
    acc[4] = fmaf(s, __uint_as_float(a.z << 16), acc[4]);
    acc[5] = fmaf(s, __uint_as_float(a.z & 0xFFFF0000u), acc[5]);
    acc[6] = fmaf(s, __uint_as_float(a.w << 16), acc[6]);
    acc[7] = fmaf(s, __uint_as_float(a.w & 0xFFFF0000u), acc[7]);
}
__device__ __forceinline__ void fmaV(float* acc, float s, float4 a, float4 b) {
    acc[0] = fmaf(s, a.x, acc[0]); acc[1] = fmaf(s, a.y, acc[1]);
    acc[2] = fmaf(s, a.z, acc[2]); acc[3] = fmaf(s, a.w, acc[3]);
    acc[4] = fmaf(s, b.x, acc[4]); acc[5] = fmaf(s, b.y, acc[5]);
    acc[6] = fmaf(s, b.z, acc[6]); acc[7] = fmaf(s, b.w, acc[7]);
}

// Q,K,V = x@W + b (relu on Q); out = hopwise[0] * V (full overwrite -> replay
// safe). Launched FIRST; side job: zero deg[].
__global__ void qkv_kernel(const float* __restrict__ x,
                           const float* __restrict__ Wq, const float* __restrict__ bq,
                           const float* __restrict__ Wk, const float* __restrict__ bk,
                           const float* __restrict__ Wv, const float* __restrict__ bv,
                           const float* __restrict__ hopwise,
                           float* __restrict__ Q, float* __restrict__ K, float* __restrict__ V,
                           float* __restrict__ out, int* __restrict__ deg, int n) {
    int idx = blockIdx.x * blockDim.x + threadIdx.x;
    if (idx < n) deg[idx] = 0;
    if (idx >= n * HIDC) return;
    int node = idx >> 6, c = idx & 63;
    const float4* x4 = (const float4*)(x + (size_t)node * HIDC);
    float aq = bq[c], ak = bk[c], av = bv[c];
    #pragma unroll
    for (int k4 = 0; k4 < 16; ++k4) {
        float4 xv = x4[k4];
        int k = k4 * 4;
        aq = fmaf(xv.x, Wq[(k + 0) * HIDC + c], aq);
        ak = fmaf(xv.x, Wk[(k + 0) * HIDC + c], ak);
        av = fmaf(xv.x, Wv[(k + 0) * HIDC + c], av);
        aq = fmaf(xv.y, Wq[(k + 1) * HIDC + c], aq);
        ak = fmaf(xv.y, Wk[(k + 1) * HIDC + c], ak);
        av = fmaf(xv.y, Wv[(k + 1) * HIDC + c], av);
        aq = fmaf(xv.z, Wq[(k + 2) * HIDC + c], aq);
        ak = fmaf(xv.z, Wk[(k + 2) * HIDC + c], ak);
        av = fmaf(xv.z, Wv[(k + 2) * HIDC + c], av);
        aq = fmaf(xv.w, Wq[(k + 3) * HIDC + c], aq);
        ak = fmaf(xv.w, Wk[(k + 3) * HIDC + c], ak);
        av = fmaf(xv.w, Wv[(k + 3) * HIDC + c], av);
    }
    Q[idx] = fmaxf(aq, 0.f);
    K[idx] = ak;
    V[idx] = av;
    out[idx] = hopwise[0] * av;
}

__global__ void deg_kernel(const int* __restrict__ col, int* __restrict__ deg, int e) {
    int i = blockIdx.x * blockDim.x + threadIdx.x;
    if (i < e) atomicAdd(&deg[col[i]], 1);
}

// exclusive prefix sum of deg -> rowptr[n+1]; also cursor[i] = rowptr[i].
__global__ __launch_bounds__(1024) void scan_kernel(const int* __restrict__ deg,
                                                    int* __restrict__ rowptr,
                                                    int* __restrict__ cursor, int n) {
    __shared__ int wsum[16];
    __shared__ int carry;
    int tid = threadIdx.x;
    int lane = tid & 63, w = tid >> 6;
    if (tid == 0) { carry = 0; rowptr[0] = 0; }
    __syncthreads();
    for (int start = 0; start < n; start += 1024) {
        int i = start + tid;
        int v = (i < n) ? deg[i] : 0;
        int s = v;
        #pragma unroll
        for (int off = 1; off < 64; off <<= 1) {
            int t = __shfl_up(s, off);
            if (lane >= off) s += t;
        }
        if (lane == 63) wsum[w] = s;
        __syncthreads();
        if (tid == 0) {
            int acc = carry;
            #pragma unroll
            for (int w2 = 0; w2 < 16; ++w2) { int t = wsum[w2]; wsum[w2] = acc; acc += t; }
            carry = acc;
        }
        __syncthreads();
        int incl = wsum[w] + s;
        if (i < n) {
            rowptr[i + 1] = incl;
            cursor[i] = incl - v;   // exclusive prefix = rowptr[i]
        }
        __syncthreads();
    }
}

// thread-per-edge: norm + CSR slot via atomic on cursor (pre-seeded to rowptr).
__global__ void pos_kernel(const int* __restrict__ row, const int* __restrict__ col,
                           const float* __restrict__ ew, const int* __restrict__ deg,
                           int* __restrict__ cursor,
                           int* __restrict__ srcrow, float* __restrict__ snorm,
                           int* __restrict__ posarr, int e) {
    int i = blockIdx.x * blockDim.x + threadIdx.x;
    if (i >= e) return;
    int r = row[i], c = col[i];
    int dr = deg[r], dc = deg[c];
    float nv = ew[i];
    nv *= (dr > 0) ? rsqrtf((float)dr) : 0.f;
    nv *= (dc > 0) ? rsqrtf((float)dc) : 0.f;
    int pos = atomicAdd(&cursor[c], 1);
    srcrow[pos] = r;
    snorm[pos] = nv;
    posarr[i] = pos;
}

// 16 threads per edge; ef read coalesced in ORIGINAL edge order (streaming),
// kjb write = one 128B line at CSR slot posarr[i] (scattered, fire-and-forget).
__global__ __launch_bounds__(256) void kj_kernel(
    const int* __restrict__ row, const int* __restrict__ posarr,
    const float* __restrict__ K, const float* __restrict__ ef,
    unsigned short* __restrict__ kjb, int e) {
    int gtid = blockIdx.x * blockDim.x + threadIdx.x;
    int i = gtid >> 4;
    if (i >= e) return;
    int c4 = gtid & 15;
    int lane = threadIdx.x & 63;
    int lanebase = lane & 48;  // first lane of this 16-thread group
    int r = 0, pos = 0;
    if (c4 == 0) { r = row[i]; pos = posarr[i]; }
    r = __shfl(r, lanebase);
    pos = __shfl(pos, lanebase);
    const float4* efv = (const float4*)ef;
    const float4* Kv = (const float4*)K;
    float4 f = efv[(size_t)i * 16 + c4];
    float4 kk = Kv[(size_t)r * 16 + c4];
    uint2 st;
    st.x = pack2(fmaxf(kk.x + f.x, 0.f), fmaxf(kk.y + f.y, 0.f));
    st.y = pack2(fmaxf(kk.z + f.z, 0.f), fmaxf(kk.w + f.w, 0.f));
    ((uint2*)kjb)[(size_t)pos * 16 + c4] = st;
}

// epilogue (64 threads/node, t = h*8+ii owns M[h][ii][0..7]):
// H = Q.M (reduce ii via xor 1/2/4), clamp-norm (j-reduce in-thread)
__device__ __forceinline__ void epilogue64(const float* acc, const float* __restrict__ Q,
                                           float hw, int n, int h, int ii,
                                           float* __restrict__ out) {
    float q = Q[n * HIDC + h * 8 + ii];
    float p[8];
    #pragma unroll
    for (int j = 0; j < 8; ++j) p[j] = q * acc[j];
    #pragma unroll
    for (int off = 1; off < 8; off <<= 1) {
        #pragma unroll
        for (int j = 0; j < 8; ++j) p[j] += __shfl_xor(p[j], off);
    }
    float ssq = 0.f;
    #pragma unroll
    for (int j = 0; j < 8; ++j) ssq = fmaf(p[j], p[j], ssq);
    float nr = sqrtf(ssq * 0.125f);
    float sc = (nr > 1.f) ? (hw / nr) : hw;
    if (ii == 0) {
        float4* o = (float4*)(out + (size_t)n * HIDC + h * 8);
        float4 c0 = o[0], c1 = o[1];
        c0.x = fmaf(p[0], sc, c0.x); c0.y = fmaf(p[1], sc, c0.y);
        c0.z = fmaf(p[2], sc, c0.z); c0.w = fmaf(p[3], sc, c0.w);
        c1.x = fmaf(p[4], sc, c1.x); c1.y = fmaf(p[5], sc, c1.y);
        c1.z = fmaf(p[6], sc, c1.z); c1.w = fmaf(p[7], sc, c1.w);
        o[0] = c0; o[1] = c1;
    }
}

// hop 0: one wave per node; streams kjb sequentially (CSR order), V gathers
// L2-resident. Unroll 4 for MLP.
__global__ __launch_bounds__(256) void hop0_kernel(
    const int* __restrict__ rowptr, const int* __restrict__ srcrow,
    const float* __restrict__ snorm, const unsigned short* __restrict__ kjb,
    const float* __restrict__ V, const float* __restrict__ Q,
    const float* __restrict__ hopwise, unsigned short* __restrict__ M0,
    float* __restrict__ out, int nn) {
    int n = blockIdx.x * 4 + (threadIdx.x >> 6);
    if (n >= nn) return;
    int t = threadIdx.x & 63;
    int h = t >> 3, ii = t & 7;
    int beg = rowptr[n], end = rowptr[n + 1];
    float acc[8] = {0, 0, 0, 0, 0, 0, 0, 0};
    const float4* Vv = (const float4*)V;
    int k = beg;
    for (; k + 4 <= end; k += 4) {
        int j0 = srcrow[k], j1 = srcrow[k + 1], j2 = srcrow[k + 2], j3 = srcrow[k + 3];
        float s0 = snorm[k]     * bfval(kjb[(size_t)(k)     * HIDC + t]);
        float s1 = snorm[k + 1] * bfval(kjb[(size_t)(k + 1) * HIDC + t]);
        float s2 = snorm[k + 2] * bfval(kjb[(size_t)(k + 2) * HIDC + t]);
        float s3 = snorm[k + 3] * bfval(kjb[(size_t)(k + 3) * HIDC + t]);
        float4 a0 = Vv[j0 * 16 + h * 2], b0 = Vv[j0 * 16 + h * 2 + 1];
        float4 a1 = Vv[j1 * 16 + h * 2], b1 = Vv[j1 * 16 + h * 2 + 1];
        float4 a2 = Vv[j2 * 16 + h * 2], b2 = Vv[j2 * 16 + h * 2 + 1];
        float4 a3 = Vv[j3 * 16 + h * 2], b3 = Vv[j3 * 16 + h * 2 + 1];
        fmaV(acc, s0, a0, b0);
        fmaV(acc, s1, a1, b1);
        fmaV(acc, s2, a2, b2);
        fmaV(acc, s3, a3, b3);
    }
    for (; k < end; ++k) {
        int j = srcrow[k];
        float s = snorm[k] * bfval(kjb[(size_t)k * HIDC + t]);
        fmaV(acc, s, Vv[j * 16 + h * 2], Vv[j * 16 + h * 2 + 1]);
    }
    uint4 st;
    st.x = pack2(acc[0], acc[1]); st.y = pack2(acc[2], acc[3]);
    st.z = pack2(acc[4], acc[5]); st.w = pack2(acc[6], acc[7]);
    ((uint4*)M0)[(size_t)n * 64 + t] = st;
    epilogue64(acc, Q, hopwise[1], n, h, ii, out);
}

// hop k>=1: Mout[n] = sum_e norm * Min[row[e]]; one wave per node, bf16 rows,
// unroll 8 for MLP on the random row gathers.
__global__ __launch_bounds__(256) void hopk_kernel(
    const int* __restrict__ rowptr, const int* __restrict__ srcrow,
    const float* __restrict__ snorm, const unsigned short* __restrict__ Min,
    const float* __restrict__ Q, const float* __restrict__ hopwise, int hopidx,
    unsigned short* __restrict__ Mout, int writeM, float* __restrict__ out, int nn) {
    int n = blockIdx.x * 4 + (threadIdx.x >> 6);
    if (n >= nn) return;
    int t = threadIdx.x & 63;
    int beg = rowptr[n], end = rowptr[n + 1];
    float acc[8] = {0, 0, 0, 0, 0, 0, 0, 0};
    const uint4* Mv = (const uint4*)Min;  // row j at Mv[j*64 + t]
    int k = beg;
    for (; k + 8 <= end; k += 8) {
        int j0 = srcrow[k],     j1 = srcrow[k + 1], j2 = srcrow[k + 2], j3 = srcrow[k + 3];
        int j4 = srcrow[k + 4], j5 = srcrow[k + 5], j6 = srcrow[k + 6], j7 = srcrow[k + 7];
        uint4 a0 = Mv[(size_t)j0 * 64 + t];
        uint4 a1 = Mv[(size_t)j1 * 64 + t];
        uint4 a2 = Mv[(size_t)j2 * 64 + t];
        uint4 a3 = Mv[(size_t)j3 * 64 + t];
        uint4 a4 = Mv[(size_t)j4 * 64 + t];
        uint4 a5 = Mv[(size_t)j5 * 64 + t];
        uint4 a6 = Mv[(size_t)j6 * 64 + t];
        uint4 a7 = Mv[(size_t)j7 * 64 + t];
        acc8(acc, snorm[k],     a0);
        acc8(acc, snorm[k + 1], a1);
        acc8(acc, snorm[k + 2], a2);
        acc8(acc, snorm[k + 3], a3);
        acc8(acc, snorm[k + 4], a4);
        acc8(acc, snorm[k + 5], a5);
        acc8(acc, snorm[k + 6], a6);
        acc8(acc, snorm[k + 7], a7);
    }
    for (; k + 4 <= end; k += 4) {
        int j0 = srcrow[k], j1 = srcrow[k + 1], j2 = srcrow[k + 2], j3 = srcrow[k + 3];
        uint4 a0 = Mv[(size_t)j0 * 64 + t];
        uint4 a1 = Mv[(size_t)j1 * 64 + t];
        uint4 a2 = Mv[(size_t)j2 * 64 + t];
        uint4 a3 = Mv[(size_t)j3 * 64 + t];
        acc8(acc, snorm[k],     a0);
        acc8(acc, snorm[k + 1], a1);
        acc8(acc, snorm[k + 2], a2);
        acc8(acc, snorm[k + 3], a3);
    }
    for (; k < end; ++k) acc8(acc, snorm[k], Mv[(size_t)srcrow[k] * 64 + t]);
    if (writeM) {
        uint4 st;
        st.x = pack2(acc[0], acc[1]); st.y = pack2(acc[2], acc[3]);
        st.z = pack2(acc[4], acc[5]); st.w = pack2(acc[6], acc[7]);
        ((uint4*)Mout)[(size_t)n * 64 + t] = st;
    }
    int h = t >> 3, ii = t & 7;
    epilogue64(acc, Q, hopwise[hopidx], n, h, ii, out);
}

extern "C" void kernel_launch(void* const* d_in, const int* in_sizes, int n_in,
                              void* d_out, int out_size, void* d_ws, size_t ws_size,
                              hipStream_t stream) {
    const float* x       = (const float*)d_in[0];
    const int*   ei      = (const int*)d_in[1];
    const float* ef      = (const float*)d_in[2];
    const float* ew      = (const float*)d_in[3];
    const float* Wq      = (const float*)d_in[4];
    const float* bq      = (const float*)d_in[5];
    const float* Wk      = (const float*)d_in[6];
    const float* bk      = (const float*)d_in[7];
    const float* Wv      = (const float*)d_in[8];
    const float* bv      = (const float*)d_in[9];
    const float* hopwise = (const float*)d_in[10];
    float* out = (float*)d_out;

    const int n = in_sizes[0] / HIDC;   // 10000
    const int e = in_sizes[1] / 2;      // 160000
    const int* row = ei;
    const int* col = ei + e;

    char* base = (char*)d_ws;
    size_t off = 0;
    auto alloc = [&](size_t bytes) -> void* {
        void* p = base + off;
        off = (off + bytes + 255) & ~(size_t)255;
        return p;
    };
    int*            deg    = (int*)           alloc((size_t)n * 4);
    int*            cursor = (int*)           alloc((size_t)n * 4);
    int*            rowptr = (int*)           alloc((size_t)(n + 1) * 4);
    int*            srcrow = (int*)           alloc((size_t)e * 4);
    float*          snorm  = (float*)         alloc((size_t)e * 4);
    int*            posarr = (int*)           alloc((size_t)e * 4);
    unsigned short* kjb    = (unsigned short*)alloc((size_t)e * HIDC * 2);
    float*          Q      = (float*)         alloc((size_t)n * HIDC * 4);
    float*          K      = (float*)         alloc((size_t)n * HIDC * 4);
    float*          V      = (float*)         alloc((size_t)n * HIDC * 4);
    unsigned short* M0     = (unsigned short*)alloc((size_t)n * MELEMS * 2);
    unsigned short* M1     = (unsigned short*)alloc((size_t)n * MELEMS * 2);
    (void)ws_size;

    int qb = (n * HIDC + 255) / 256;
    qkv_kernel<<<qb, 256, 0, stream>>>(x, Wq, bq, Wk, bk, Wv, bv, hopwise,
                                       Q, K, V, out, deg, n);

    int eb = (e + 255) / 256;
    deg_kernel<<<eb, 256, 0, stream>>>(col, deg, e);
    scan_kernel<<<1, 1024, 0, stream>>>(deg, rowptr, cursor, n);

    pos_kernel<<<eb, 256, 0, stream>>>(row, col, ew, deg, cursor,
                                       srcrow, snorm, posarr, e);
    int kb = ((e * 16) + 255) / 256;
    kj_kernel<<<kb, 256, 0, stream>>>(row, posarr, K, ef, kjb, e);

    int nb = (n + 3) / 4;
    hop0_kernel<<<nb, 256, 0, stream>>>(rowptr, srcrow, snorm, kjb, V, Q,
                                        hopwise, M0, out, n);
    hopk_kernel<<<nb, 256, 0, stream>>>(rowptr, srcrow, snorm, M0, Q, hopwise, 2, M1, 1, out, n);
    hopk_kernel<<<nb, 256, 0, stream>>>(rowptr, srcrow, snorm, M1, Q, hopwise, 3, M0, 0, out, n);
}

// Round 9
// 134.400 us; speedup vs baseline: 1.0542x; 1.0542x over previous
//
#include <hip/hip_runtime.h>
#include <hip/hip_bf16.h>

// MSTAGNN: N=10000, E=160000, HID=64, HEADS=8, D=8, KHOPS=3.
// R9: stage BOTH relu(K[row]+ef) and V[row] as one interleaved bf16 CSR row
// (kjv[pos] = [kj 64bf16 | V 64bf16] = 256B) so hop0 is a single fully
// sequential stream with ZERO gathers (R7 lesson: 3 random gathers/edge =
// 1.5TB/s latency-bound = 44us). Parallel CSR base allocation via per-block
// scan + atomic counter (replaces serial single-block scan); hop kernels use
// beg=rowbeg[n], end=beg+deg[n] (no global monotonicity needed).
// M propagated as bf16 rows, one wave per node, f32 accumulation.
// No memsets (deg+counter zeroed in qkv). K-propagation in ref is dead code.

#define HIDC 64
#define MELEMS 512  // HEADS * D * D

__device__ __forceinline__ unsigned bf16rne(float x) {
    unsigned u = __float_as_uint(x);
    return (u + 0x7FFFu + ((u >> 16) & 1u)) >> 16;
}
__device__ __forceinline__ unsigned pack2(float lo, float hi) {
    return bf16rne(lo) | (bf16rne(hi) << 16);
}
__device__ __forceinline__ float bfval(unsigned short v) {
    return __uint_as_float((unsigned)v << 16);
}
__device__ __forceinline__ void acc8(float* acc, float s, uint4 a) {
    acc[0] = fmaf(s, __uint_as_float(a.x << 16), acc[0]);
    acc[1] = fmaf(s, __uint_as_float(a.x & 0xFFFF0000u), acc[1]);
    acc[2] = fmaf(s, __uint_as_float(a.y << 16), acc[2]);
    acc[3] = fmaf(s, __uint_as_float(a.y & 0xFFFF0000u), acc[3]);
    acc[4] = fmaf(s, __uint_as_float(a.z << 16), acc[4]);
    acc[5] = fmaf(s, __uint_as_float(a.z & 0xFFFF0000u), acc[5]);
    acc[6] = fmaf(s, __uint_as_float(a.w << 16), acc[6]);
    acc[7] = fmaf(s, __uint_as_float(a.w & 0xFFFF0000u), acc[7]);
}

// Q,K,V = x@W + b (relu on Q); out = hopwise[0] * V (full overwrite -> replay
// safe). Launched FIRST; side jobs: zero deg[] and the CSR base counter.
__global__ void qkv_kernel(const float* __restrict__ x,
                           const float* __restrict__ Wq, const float* __restrict__ bq,
                           const float* __restrict__ Wk, const float* __restrict__ bk,
                           const float* __restrict__ Wv, const float* __restrict__ bv,
                           const float* __restrict__ hopwise,
                           float* __restrict__ Q, float* __restrict__ K, float* __restrict__ V,
                           float* __restrict__ out, int* __restrict__ deg,
                           int* __restrict__ counter, int n) {
    int idx = blockIdx.x * blockDim.x + threadIdx.x;
    if (idx < n) deg[idx] = 0;
    if (idx == 0) *counter = 0;
    if (idx >= n * HIDC) return;
    int node = idx >> 6, c = idx & 63;
    const float4* x4 = (const float4*)(x + (size_t)node * HIDC);
    float aq = bq[c], ak = bk[c], av = bv[c];
    #pragma unroll
    for (int k4 = 0; k4 < 16; ++k4) {
        float4 xv = x4[k4];
        int k = k4 * 4;
        aq = fmaf(xv.x, Wq[(k + 0) * HIDC + c], aq);
        ak = fmaf(xv.x, Wk[(k + 0) * HIDC + c], ak);
        av = fmaf(xv.x, Wv[(k + 0) * HIDC + c], av);
        aq = fmaf(xv.y, Wq[(k + 1) * HIDC + c], aq);
        ak = fmaf(xv.y, Wk[(k + 1) * HIDC + c], ak);
        av = fmaf(xv.y, Wv[(k + 1) * HIDC + c], av);
        aq = fmaf(xv.z, Wq[(k + 2) * HIDC + c], aq);
        ak = fmaf(xv.z, Wk[(k + 2) * HIDC + c], ak);
        av = fmaf(xv.z, Wv[(k + 2) * HIDC + c], av);
        aq = fmaf(xv.w, Wq[(k + 3) * HIDC + c], aq);
        ak = fmaf(xv.w, Wk[(k + 3) * HIDC + c], ak);
        av = fmaf(xv.w, Wv[(k + 3) * HIDC + c], av);
    }
    Q[idx] = fmaxf(aq, 0.f);
    K[idx] = ak;
    V[idx] = av;
    out[idx] = hopwise[0] * av;
}

__global__ void deg_kernel(const int* __restrict__ col, int* __restrict__ deg, int e) {
    int i = blockIdx.x * blockDim.x + threadIdx.x;
    if (i < e) atomicAdd(&deg[col[i]], 1);
}

// parallel CSR base allocation: per-1024-node block scan + atomic block base.
// rowbeg[i] = cursor[i] = global slot base for node i (NOT globally monotone;
// hop kernels use end = rowbeg[n] + deg[n]).
__global__ __launch_bounds__(1024) void base_kernel(const int* __restrict__ deg,
                                                    int* __restrict__ counter,
                                                    int* __restrict__ rowbeg,
                                                    int* __restrict__ cursor, int n) {
    __shared__ int wsum[16];
    __shared__ int blockbase;
    int i = blockIdx.x * 1024 + threadIdx.x;
    int lane = threadIdx.x & 63, w = threadIdx.x >> 6;
    int v = (i < n) ? deg[i] : 0;
    int s = v;
    #pragma unroll
    for (int off = 1; off < 64; off <<= 1) {
        int t = __shfl_up(s, off);
        if (lane >= off) s += t;
    }
    if (lane == 63) wsum[w] = s;
    __syncthreads();
    if (threadIdx.x == 0) {
        int acc = 0;
        #pragma unroll
        for (int w2 = 0; w2 < 16; ++w2) { int t = wsum[w2]; wsum[w2] = acc; acc += t; }
        blockbase = atomicAdd(counter, acc);
    }
    __syncthreads();
    int excl = blockbase + wsum[w] + s - v;
    if (i < n) {
        rowbeg[i] = excl;
        cursor[i] = excl;
    }
}

// thread-per-edge: norm + CSR slot via atomic on cursor (pre-seeded to base).
__global__ void pos_kernel(const int* __restrict__ row, const int* __restrict__ col,
                           const float* __restrict__ ew, const int* __restrict__ deg,
                           int* __restrict__ cursor,
                           int* __restrict__ srcrow, float* __restrict__ snorm,
                           int* __restrict__ posarr, int e) {
    int i = blockIdx.x * blockDim.x + threadIdx.x;
    if (i >= e) return;
    int r = row[i], c = col[i];
    int dr = deg[r], dc = deg[c];
    float nv = ew[i];
    nv *= (dr > 0) ? rsqrtf((float)dr) : 0.f;
    nv *= (dc > 0) ? rsqrtf((float)dc) : 0.f;
    int pos = atomicAdd(&cursor[c], 1);
    srcrow[pos] = r;
    snorm[pos] = nv;
    posarr[i] = pos;
}

// 16 threads/edge: stage kjv[pos] = [relu(K[r]+ef[i]) 64bf16 | V[r] 64bf16]
// (256B row). ef read sequential/coalesced; K,V gathers L2-resident; writes
// are two uint2 per thread into one 256B row (coalesced per group).
__global__ __launch_bounds__(256) void kjv_kernel(
    const int* __restrict__ row, const int* __restrict__ posarr,
    const float* __restrict__ K, const float* __restrict__ V,
    const float* __restrict__ ef, unsigned short* __restrict__ kjv, int e) {
    int gtid = blockIdx.x * blockDim.x + threadIdx.x;
    int i = gtid >> 4;
    if (i >= e) return;
    int c4 = gtid & 15;
    int lanebase = (threadIdx.x & 63) & 48;
    int r = 0, pos = 0;
    if (c4 == 0) { r = row[i]; pos = posarr[i]; }
    r = __shfl(r, lanebase);
    pos = __shfl(pos, lanebase);
    const float4* efv = (const float4*)ef;
    const float4* Kv = (const float4*)K;
    const float4* Vv = (const float4*)V;
    float4 f = efv[(size_t)i * 16 + c4];
    float4 kk = Kv[(size_t)r * 16 + c4];
    float4 vv = Vv[(size_t)r * 16 + c4];
    uint2 kjp, vp;
    kjp.x = pack2(fmaxf(kk.x + f.x, 0.f), fmaxf(kk.y + f.y, 0.f));
    kjp.y = pack2(fmaxf(kk.z + f.z, 0.f), fmaxf(kk.w + f.w, 0.f));
    vp.x = pack2(vv.x, vv.y);
    vp.y = pack2(vv.z, vv.w);
    uint2* rowp = (uint2*)(kjv + (size_t)pos * 128);  // 128 ushorts = 256B
    rowp[c4] = kjp;        // kj channels 4c4..4c4+3
    rowp[16 + c4] = vp;    // V  channels 4c4..4c4+3
}

// epilogue (64 threads/node, t = h*8+ii owns M[h][ii][0..7]):
// H = Q.M (reduce ii via xor 1/2/4), clamp-norm (j-reduce in-thread)
__device__ __forceinline__ void epilogue64(const float* acc, const float* __restrict__ Q,
                                           float hw, int n, int h, int ii,
                                           float* __restrict__ out) {
    float q = Q[n * HIDC + h * 8 + ii];
    float p[8];
    #pragma unroll
    for (int j = 0; j < 8; ++j) p[j] = q * acc[j];
    #pragma unroll
    for (int off = 1; off < 8; off <<= 1) {
        #pragma unroll
        for (int j = 0; j < 8; ++j) p[j] += __shfl_xor(p[j], off);
    }
    float ssq = 0.f;
    #pragma unroll
    for (int j = 0; j < 8; ++j) ssq = fmaf(p[j], p[j], ssq);
    float nr = sqrtf(ssq * 0.125f);
    float sc = (nr > 1.f) ? (hw / nr) : hw;
    if (ii == 0) {
        float4* o = (float4*)(out + (size_t)n * HIDC + h * 8);
        float4 c0 = o[0], c1 = o[1];
        c0.x = fmaf(p[0], sc, c0.x); c0.y = fmaf(p[1], sc, c0.y);
        c0.z = fmaf(p[2], sc, c0.z); c0.w = fmaf(p[3], sc, c0.w);
        c1.x = fmaf(p[4], sc, c1.x); c1.y = fmaf(p[5], sc, c1.y);
        c1.z = fmaf(p[6], sc, c1.z); c1.w = fmaf(p[7], sc, c1.w);
        o[0] = c0; o[1] = c1;
    }
}

// hop 0: one wave per node; kjv stream is 100% sequential (2 loads/edge:
// ushort kj + uint4 V-half-row broadcast), no gathers at all. Unroll 4.
__global__ __launch_bounds__(256) void hop0_kernel(
    const int* __restrict__ rowbeg, const int* __restrict__ deg,
    const float* __restrict__ snorm, const unsigned short* __restrict__ kjv,
    const float* __restrict__ Q, const float* __restrict__ hopwise,
    unsigned short* __restrict__ M0, float* __restrict__ out, int nn) {
    int n = blockIdx.x * 4 + (threadIdx.x >> 6);
    if (n >= nn) return;
    int t = threadIdx.x & 63;
    int h = t >> 3, ii = t & 7;
    int beg = rowbeg[n], end = beg + deg[n];
    float acc[8] = {0, 0, 0, 0, 0, 0, 0, 0};
    int k = beg;
    for (; k + 4 <= end; k += 4) {
        float s0 = snorm[k]     * bfval(kjv[(size_t)(k)     * 128 + t]);
        float s1 = snorm[k + 1] * bfval(kjv[(size_t)(k + 1) * 128 + t]);
        float s2 = snorm[k + 2] * bfval(kjv[(size_t)(k + 2) * 128 + t]);
        float s3 = snorm[k + 3] * bfval(kjv[(size_t)(k + 3) * 128 + t]);
        uint4 v0 = *(const uint4*)(kjv + (size_t)(k)     * 128 + 64 + h * 8);
        uint4 v1 = *(const uint4*)(kjv + (size_t)(k + 1) * 128 + 64 + h * 8);
        uint4 v2 = *(const uint4*)(kjv + (size_t)(k + 2) * 128 + 64 + h * 8);
        uint4 v3 = *(const uint4*)(kjv + (size_t)(k + 3) * 128 + 64 + h * 8);
        acc8(acc, s0, v0);
        acc8(acc, s1, v1);
        acc8(acc, s2, v2);
        acc8(acc, s3, v3);
    }
    for (; k < end; ++k) {
        float s = snorm[k] * bfval(kjv[(size_t)k * 128 + t]);
        uint4 v = *(const uint4*)(kjv + (size_t)k * 128 + 64 + h * 8);
        acc8(acc, s, v);
    }
    uint4 st;
    st.x = pack2(acc[0], acc[1]); st.y = pack2(acc[2], acc[3]);
    st.z = pack2(acc[4], acc[5]); st.w = pack2(acc[6], acc[7]);
    ((uint4*)M0)[(size_t)n * 64 + t] = st;
    epilogue64(acc, Q, hopwise[1], n, h, ii, out);
}

// hop k>=1: Mout[n] = sum_e norm * Min[row[e]]; one wave per node, bf16 rows,
// unroll 8 for MLP on the random row gathers.
__global__ __launch_bounds__(256) void hopk_kernel(
    const int* __restrict__ rowbeg, const int* __restrict__ deg,
    const int* __restrict__ srcrow, const float* __restrict__ snorm,
    const unsigned short* __restrict__ Min, const float* __restrict__ Q,
    const float* __restrict__ hopwise, int hopidx,
    unsigned short* __restrict__ Mout, int writeM, float* __restrict__ out, int nn) {
    int n = blockIdx.x * 4 + (threadIdx.x >> 6);
    if (n >= nn) return;
    int t = threadIdx.x & 63;
    int beg = rowbeg[n], end = beg + deg[n];
    float acc[8] = {0, 0, 0, 0, 0, 0, 0, 0};
    const uint4* Mv = (const uint4*)Min;  // row j at Mv[j*64 + t]
    int k = beg;
    for (; k + 8 <= end; k += 8) {
        int j0 = srcrow[k],     j1 = srcrow[k + 1], j2 = srcrow[k + 2], j3 = srcrow[k + 3];
        int j4 = srcrow[k + 4], j5 = srcrow[k + 5], j6 = srcrow[k + 6], j7 = srcrow[k + 7];
        uint4 a0 = Mv[(size_t)j0 * 64 + t];
        uint4 a1 = Mv[(size_t)j1 * 64 + t];
        uint4 a2 = Mv[(size_t)j2 * 64 + t];
        uint4 a3 = Mv[(size_t)j3 * 64 + t];
        uint4 a4 = Mv[(size_t)j4 * 64 + t];
        uint4 a5 = Mv[(size_t)j5 * 64 + t];
        uint4 a6 = Mv[(size_t)j6 * 64 + t];
        uint4 a7 = Mv[(size_t)j7 * 64 + t];
        acc8(acc, snorm[k],     a0);
        acc8(acc, snorm[k + 1], a1);
        acc8(acc, snorm[k + 2], a2);
        acc8(acc, snorm[k + 3], a3);
        acc8(acc, snorm[k + 4], a4);
        acc8(acc, snorm[k + 5], a5);
        acc8(acc, snorm[k + 6], a6);
        acc8(acc, snorm[k + 7], a7);
    }
    for (; k + 4 <= end; k += 4) {
        int j0 = srcrow[k], j1 = srcrow[k + 1], j2 = srcrow[k + 2], j3 = srcrow[k + 3];
        uint4 a0 = Mv[(size_t)j0 * 64 + t];
        uint4 a1 = Mv[(size_t)j1 * 64 + t];
        uint4 a2 = Mv[(size_t)j2 * 64 + t];
        uint4 a3 = Mv[(size_t)j3 * 64 + t];
        acc8(acc, snorm[k],     a0);
        acc8(acc, snorm[k + 1], a1);
        acc8(acc, snorm[k + 2], a2);
        acc8(acc, snorm[k + 3], a3);
    }
    for (; k < end; ++k) acc8(acc, snorm[k], Mv[(size_t)srcrow[k] * 64 + t]);
    if (writeM) {
        uint4 st;
        st.x = pack2(acc[0], acc[1]); st.y = pack2(acc[2], acc[3]);
        st.z = pack2(acc[4], acc[5]); st.w = pack2(acc[6], acc[7]);
        ((uint4*)Mout)[(size_t)n * 64 + t] = st;
    }
    int h = t >> 3, ii = t & 7;
    epilogue64(acc, Q, hopwise[hopidx], n, h, ii, out);
}

extern "C" void kernel_launch(void* const* d_in, const int* in_sizes, int n_in,
                              void* d_out, int out_size, void* d_ws, size_t ws_size,
                              hipStream_t stream) {
    const float* x       = (const float*)d_in[0];
    const int*   ei      = (const int*)d_in[1];
    const float* ef      = (const float*)d_in[2];
    const float* ew      = (const float*)d_in[3];
    const float* Wq      = (const float*)d_in[4];
    const float* bq      = (const float*)d_in[5];
    const float* Wk      = (const float*)d_in[6];
    const float* bk      = (const float*)d_in[7];
    const float* Wv      = (const float*)d_in[8];
    const float* bv      = (const float*)d_in[9];
    const float* hopwise = (const float*)d_in[10];
    float* out = (float*)d_out;

    const int n = in_sizes[0] / HIDC;   // 10000
    const int e = in_sizes[1] / 2;      // 160000
    const int* row = ei;
    const int* col = ei + e;

    char* base = (char*)d_ws;
    size_t off = 0;
    auto alloc = [&](size_t bytes) -> void* {
        void* p = base + off;
        off = (off + bytes + 255) & ~(size_t)255;
        return p;
    };
    int*            deg     = (int*)           alloc((size_t)n * 4);
    int*            cursor  = (int*)           alloc((size_t)n * 4);
    int*            rowbeg  = (int*)           alloc((size_t)n * 4);
    int*            counter = (int*)           alloc(256);
    int*            srcrow  = (int*)           alloc((size_t)e * 4);
    float*          snorm   = (float*)         alloc((size_t)e * 4);
    int*            posarr  = (int*)           alloc((size_t)e * 4);
    unsigned short* kjv     = (unsigned short*)alloc((size_t)e * 128 * 2);
    float*          Q       = (float*)         alloc((size_t)n * HIDC * 4);
    float*          K       = (float*)         alloc((size_t)n * HIDC * 4);
    float*          V       = (float*)         alloc((size_t)n * HIDC * 4);
    unsigned short* M0      = (unsigned short*)alloc((size_t)n * MELEMS * 2);
    unsigned short* M1      = (unsigned short*)alloc((size_t)n * MELEMS * 2);
    (void)ws_size;

    int qb = (n * HIDC + 255) / 256;
    qkv_kernel<<<qb, 256, 0, stream>>>(x, Wq, bq, Wk, bk, Wv, bv, hopwise,
                                       Q, K, V, out, deg, counter, n);

    int eb = (e + 255) / 256;
    deg_kernel<<<eb, 256, 0, stream>>>(col, deg, e);

    int bb = (n + 1023) / 1024;
    base_kernel<<<bb, 1024, 0, stream>>>(deg, counter, rowbeg, cursor, n);

    pos_kernel<<<eb, 256, 0, stream>>>(row, col, ew, deg, cursor,
                                       srcrow, snorm, posarr, e);

    int kb = ((e * 16) + 255) / 256;
    kjv_kernel<<<kb, 256, 0, stream>>>(row, posarr, K, V, ef, kjv, e);

    int nb = (n + 3) / 4;
    hop0_kernel<<<nb, 256, 0, stream>>>(rowbeg, deg, snorm, kjv, Q, hopwise, M0, out, n);
    hopk_kernel<<<nb, 256, 0, stream>>>(rowbeg, deg, srcrow, snorm, M0, Q, hopwise, 2, M1, 1, out, n);
    hopk_kernel<<<nb, 256, 0, stream>>>(rowbeg, deg, srcrow, snorm, M1, Q, hopwise, 3, M0, 0, out, n);
}

// Round 10
// 127.585 us; speedup vs baseline: 1.1105x; 1.0534x over previous
//
#include <hip/hip_runtime.h>
#include <hip/hip_bf16.h>

// MSTAGNN: N=10000, E=160000, HID=64, HEADS=8, D=8, KHOPS=3.
// R10: (1) pos_kernel fused into the staging kernel (leader lane of each
// 16-thread edge-group does norm+atomic slot, then all 16 stage the 256B
// kjv row) -- one less launch, no posarr round-trip. (2) qkv rewritten with
// 4 nodes/thread so W streams from L2 once per 4 nodes (was once per node,
// ~480MB L2 traffic). kjv = [relu(K[r]+ef) 64bf16 | V[r] 64bf16] per CSR
// slot; hop0 is a pure sequential stream with zero gathers. M propagated as
// bf16 rows, one wave/node, f32 accum. No memsets. K-prop is dead code.

#define HIDC 64
#define MELEMS 512  // HEADS * D * D

__device__ __forceinline__ unsigned bf16rne(float x) {
    unsigned u = __float_as_uint(x);
    return (u + 0x7FFFu + ((u >> 16) & 1u)) >> 16;
}
__device__ __forceinline__ unsigned pack2(float lo, float hi) {
    return bf16rne(lo) | (bf16rne(hi) << 16);
}
__device__ __forceinline__ float bfval(unsigned short v) {
    return __uint_as_float((unsigned)v << 16);
}
__device__ __forceinline__ void acc8(float* acc, float s, uint4 a) {
    acc[0] = fmaf(s, __uint_as_float(a.x << 16), acc[0]);
    acc[1] = fmaf(s, __uint_as_float(a.x & 0xFFFF0000u), acc[1]);
    acc[2] = fmaf(s, __uint_as_float(a.y << 16), acc[2]);
    acc[3] = fmaf(s, __uint_as_float(a.y & 0xFFFF0000u), acc[3]);
    acc[4] = fmaf(s, __uint_as_float(a.z << 16), acc[4]);
    acc[5] = fmaf(s, __uint_as_float(a.z & 0xFFFF0000u), acc[5]);
    acc[6] = fmaf(s, __uint_as_float(a.w << 16), acc[6]);
    acc[7] = fmaf(s, __uint_as_float(a.w & 0xFFFF0000u), acc[7]);
}

// Q,K,V = x@W + b (relu on Q); out = hopwise[0]*V (full overwrite -> replay
// safe). 4 nodes per thread: W column read once per 4 nodes (L2 traffic /4).
// Side jobs: zero deg[] and the CSR base counter.
__global__ __launch_bounds__(256) void qkv_kernel(
    const float* __restrict__ x,
    const float* __restrict__ Wq, const float* __restrict__ bq,
    const float* __restrict__ Wk, const float* __restrict__ bk,
    const float* __restrict__ Wv, const float* __restrict__ bv,
    const float* __restrict__ hopwise,
    float* __restrict__ Q, float* __restrict__ K, float* __restrict__ V,
    float* __restrict__ out, int* __restrict__ deg,
    int* __restrict__ counter, int n) {
    int gid = blockIdx.x * blockDim.x + threadIdx.x;
    if (gid < n) deg[gid] = 0;
    if (gid == 0) *counter = 0;
    int c = gid & 63;
    int nb = (gid >> 6) * 4;
    if (nb >= n) return;
    int mcnt = min(4, n - nb);
    float aq[4], ak[4], av[4];
    #pragma unroll
    for (int m = 0; m < 4; ++m) { aq[m] = bq[c]; ak[m] = bk[c]; av[m] = bv[c]; }
    const float4* x4 = (const float4*)x;
    for (int k4 = 0; k4 < 16; ++k4) {
        float4 xv[4];
        #pragma unroll
        for (int m = 0; m < 4; ++m)
            xv[m] = x4[(size_t)(nb + (m < mcnt ? m : 0)) * 16 + k4];
        #pragma unroll
        for (int kk = 0; kk < 4; ++kk) {
            int k = k4 * 4 + kk;
            float wq = Wq[k * HIDC + c], wk = Wk[k * HIDC + c], wv = Wv[k * HIDC + c];
            #pragma unroll
            for (int m = 0; m < 4; ++m) {
                float xvk = (kk == 0) ? xv[m].x : (kk == 1) ? xv[m].y
                          : (kk == 2) ? xv[m].z : xv[m].w;
                aq[m] = fmaf(xvk, wq, aq[m]);
                ak[m] = fmaf(xvk, wk, ak[m]);
                av[m] = fmaf(xvk, wv, av[m]);
            }
        }
    }
    #pragma unroll
    for (int m = 0; m < 4; ++m) {
        if (m < mcnt) {
            size_t idx = (size_t)(nb + m) * HIDC + c;
            Q[idx] = fmaxf(aq[m], 0.f);
            K[idx] = ak[m];
            V[idx] = av[m];
            out[idx] = hopwise[0] * av[m];
        }
    }
}

__global__ void deg_kernel(const int* __restrict__ col, int* __restrict__ deg, int e) {
    int i = blockIdx.x * blockDim.x + threadIdx.x;
    if (i < e) atomicAdd(&deg[col[i]], 1);
}

// parallel CSR base allocation: per-1024-node block scan + atomic block base.
// rowbeg[i] = cursor[i] = global slot base for node i (NOT globally monotone;
// hop kernels use end = rowbeg[n] + deg[n]).
__global__ __launch_bounds__(1024) void base_kernel(const int* __restrict__ deg,
                                                    int* __restrict__ counter,
                                                    int* __restrict__ rowbeg,
                                                    int* __restrict__ cursor, int n) {
    __shared__ int wsum[16];
    __shared__ int blockbase;
    int i = blockIdx.x * 1024 + threadIdx.x;
    int lane = threadIdx.x & 63, w = threadIdx.x >> 6;
    int v = (i < n) ? deg[i] : 0;
    int s = v;
    #pragma unroll
    for (int off = 1; off < 64; off <<= 1) {
        int t = __shfl_up(s, off);
        if (lane >= off) s += t;
    }
    if (lane == 63) wsum[w] = s;
    __syncthreads();
    if (threadIdx.x == 0) {
        int acc = 0;
        #pragma unroll
        for (int w2 = 0; w2 < 16; ++w2) { int t = wsum[w2]; wsum[w2] = acc; acc += t; }
        blockbase = atomicAdd(counter, acc);
    }
    __syncthreads();
    int excl = blockbase + wsum[w] + s - v;
    if (i < n) {
        rowbeg[i] = excl;
        cursor[i] = excl;
    }
}

// fused pos+stage: 16 threads/edge. Leader (c4==0) computes norm + CSR slot
// (atomic) and writes srcrow/snorm; all 16 lanes stage kjv[pos] =
// [relu(K[r]+ef[i]) 64bf16 | V[r] 64bf16] (256B row). ef read sequential;
// K,V gathers L2-resident; atomic latency hidden by 2.56M-thread TLP.
__global__ __launch_bounds__(256) void stage_kernel(
    const int* __restrict__ row, const int* __restrict__ col,
    const float* __restrict__ ew, const int* __restrict__ deg,
    int* __restrict__ cursor, int* __restrict__ srcrow,
    float* __restrict__ snorm,
    const float* __restrict__ K, const float* __restrict__ V,
    const float* __restrict__ ef, unsigned short* __restrict__ kjv, int e) {
    int gtid = blockIdx.x * blockDim.x + threadIdx.x;
    int i = gtid >> 4;
    if (i >= e) return;
    int c4 = gtid & 15;
    int lane = threadIdx.x & 63;
    int lb = lane & 48;  // leader lane of this 16-thread group
    int r = 0, pos = 0;
    if (c4 == 0) {
        r = row[i];
        int cc = col[i];
        int dr = deg[r], dc = deg[cc];
        float nv = ew[i];
        nv *= (dr > 0) ? rsqrtf((float)dr) : 0.f;
        nv *= (dc > 0) ? rsqrtf((float)dc) : 0.f;
        pos = atomicAdd(&cursor[cc], 1);
        srcrow[pos] = r;
        snorm[pos] = nv;
    }
    r = __shfl(r, lb);
    pos = __shfl(pos, lb);
    const float4* efv = (const float4*)ef;
    const float4* Kv = (const float4*)K;
    const float4* Vv = (const float4*)V;
    float4 f = efv[(size_t)i * 16 + c4];
    float4 kk = Kv[(size_t)r * 16 + c4];
    float4 vv = Vv[(size_t)r * 16 + c4];
    uint2 kjp, vp;
    kjp.x = pack2(fmaxf(kk.x + f.x, 0.f), fmaxf(kk.y + f.y, 0.f));
    kjp.y = pack2(fmaxf(kk.z + f.z, 0.f), fmaxf(kk.w + f.w, 0.f));
    vp.x = pack2(vv.x, vv.y);
    vp.y = pack2(vv.z, vv.w);
    uint2* rowp = (uint2*)(kjv + (size_t)pos * 128);  // 128 ushorts = 256B
    rowp[c4] = kjp;        // kj channels 4c4..4c4+3
    rowp[16 + c4] = vp;    // V  channels 4c4..4c4+3
}

// epilogue (64 threads/node, t = h*8+ii owns M[h][ii][0..7]):
// H = Q.M (reduce ii via xor 1/2/4), clamp-norm (j-reduce in-thread)
__device__ __forceinline__ void epilogue64(const float* acc, const float* __restrict__ Q,
                                           float hw, int n, int h, int ii,
                                           float* __restrict__ out) {
    float q = Q[n * HIDC + h * 8 + ii];
    float p[8];
    #pragma unroll
    for (int j = 0; j < 8; ++j) p[j] = q * acc[j];
    #pragma unroll
    for (int off = 1; off < 8; off <<= 1) {
        #pragma unroll
        for (int j = 0; j < 8; ++j) p[j] += __shfl_xor(p[j], off);
    }
    float ssq = 0.f;
    #pragma unroll
    for (int j = 0; j < 8; ++j) ssq = fmaf(p[j], p[j], ssq);
    float nr = sqrtf(ssq * 0.125f);
    float sc = (nr > 1.f) ? (hw / nr) : hw;
    if (ii == 0) {
        float4* o = (float4*)(out + (size_t)n * HIDC + h * 8);
        float4 c0 = o[0], c1 = o[1];
        c0.x = fmaf(p[0], sc, c0.x); c0.y = fmaf(p[1], sc, c0.y);
        c0.z = fmaf(p[2], sc, c0.z); c0.w = fmaf(p[3], sc, c0.w);
        c1.x = fmaf(p[4], sc, c1.x); c1.y = fmaf(p[5], sc, c1.y);
        c1.z = fmaf(p[6], sc, c1.z); c1.w = fmaf(p[7], sc, c1.w);
        o[0] = c0; o[1] = c1;
    }
}

// hop 0: one wave per node; kjv stream is 100% sequential (2 loads/edge:
// ushort kj + uint4 V-half-row broadcast), no gathers at all. Unroll 4.
__global__ __launch_bounds__(256) void hop0_kernel(
    const int* __restrict__ rowbeg, const int* __restrict__ deg,
    const float* __restrict__ snorm, const unsigned short* __restrict__ kjv,
    const float* __restrict__ Q, const float* __restrict__ hopwise,
    unsigned short* __restrict__ M0, float* __restrict__ out, int nn) {
    int n = blockIdx.x * 4 + (threadIdx.x >> 6);
    if (n >= nn) return;
    int t = threadIdx.x & 63;
    int h = t >> 3, ii = t & 7;
    int beg = rowbeg[n], end = beg + deg[n];
    float acc[8] = {0, 0, 0, 0, 0, 0, 0, 0};
    int k = beg;
    for (; k + 4 <= end; k += 4) {
        float s0 = snorm[k]     * bfval(kjv[(size_t)(k)     * 128 + t]);
        float s1 = snorm[k + 1] * bfval(kjv[(size_t)(k + 1) * 128 + t]);
        float s2 = snorm[k + 2] * bfval(kjv[(size_t)(k + 2) * 128 + t]);
        float s3 = snorm[k + 3] * bfval(kjv[(size_t)(k + 3) * 128 + t]);
        uint4 v0 = *(const uint4*)(kjv + (size_t)(k)     * 128 + 64 + h * 8);
        uint4 v1 = *(const uint4*)(kjv + (size_t)(k + 1) * 128 + 64 + h * 8);
        uint4 v2 = *(const uint4*)(kjv + (size_t)(k + 2) * 128 + 64 + h * 8);
        uint4 v3 = *(const uint4*)(kjv + (size_t)(k + 3) * 128 + 64 + h * 8);
        acc8(acc, s0, v0);
        acc8(acc, s1, v1);
        acc8(acc, s2, v2);
        acc8(acc, s3, v3);
    }
    for (; k < end; ++k) {
        float s = snorm[k] * bfval(kjv[(size_t)k * 128 + t]);
        uint4 v = *(const uint4*)(kjv + (size_t)k * 128 + 64 + h * 8);
        acc8(acc, s, v);
    }
    uint4 st;
    st.x = pack2(acc[0], acc[1]); st.y = pack2(acc[2], acc[3]);
    st.z = pack2(acc[4], acc[5]); st.w = pack2(acc[6], acc[7]);
    ((uint4*)M0)[(size_t)n * 64 + t] = st;
    epilogue64(acc, Q, hopwise[1], n, h, ii, out);
}

// hop k>=1: Mout[n] = sum_e norm * Min[row[e]]; one wave per node, bf16 rows,
// unroll 8 for MLP on the random row gathers.
__global__ __launch_bounds__(256) void hopk_kernel(
    const int* __restrict__ rowbeg, const int* __restrict__ deg,
    const int* __restrict__ srcrow, const float* __restrict__ snorm,
    const unsigned short* __restrict__ Min, const float* __restrict__ Q,
    const float* __restrict__ hopwise, int hopidx,
    unsigned short* __restrict__ Mout, int writeM, float* __restrict__ out, int nn) {
    int n = blockIdx.x * 4 + (threadIdx.x >> 6);
    if (n >= nn) return;
    int t = threadIdx.x & 63;
    int beg = rowbeg[n], end = beg + deg[n];
    float acc[8] = {0, 0, 0, 0, 0, 0, 0, 0};
    const uint4* Mv = (const uint4*)Min;  // row j at Mv[j*64 + t]
    int k = beg;
    for (; k + 8 <= end; k += 8) {
        int j0 = srcrow[k],     j1 = srcrow[k + 1], j2 = srcrow[k + 2], j3 = srcrow[k + 3];
        int j4 = srcrow[k + 4], j5 = srcrow[k + 5], j6 = srcrow[k + 6], j7 = srcrow[k + 7];
        uint4 a0 = Mv[(size_t)j0 * 64 + t];
        uint4 a1 = Mv[(size_t)j1 * 64 + t];
        uint4 a2 = Mv[(size_t)j2 * 64 + t];
        uint4 a3 = Mv[(size_t)j3 * 64 + t];
        uint4 a4 = Mv[(size_t)j4 * 64 + t];
        uint4 a5 = Mv[(size_t)j5 * 64 + t];
        uint4 a6 = Mv[(size_t)j6 * 64 + t];
        uint4 a7 = Mv[(size_t)j7 * 64 + t];
        acc8(acc, snorm[k],     a0);
        acc8(acc, snorm[k + 1], a1);
        acc8(acc, snorm[k + 2], a2);
        acc8(acc, snorm[k + 3], a3);
        acc8(acc, snorm[k + 4], a4);
        acc8(acc, snorm[k + 5], a5);
        acc8(acc, snorm[k + 6], a6);
        acc8(acc, snorm[k + 7], a7);
    }
    for (; k + 4 <= end; k += 4) {
        int j0 = srcrow[k], j1 = srcrow[k + 1], j2 = srcrow[k + 2], j3 = srcrow[k + 3];
        uint4 a0 = Mv[(size_t)j0 * 64 + t];
        uint4 a1 = Mv[(size_t)j1 * 64 + t];
        uint4 a2 = Mv[(size_t)j2 * 64 + t];
        uint4 a3 = Mv[(size_t)j3 * 64 + t];
        acc8(acc, snorm[k],     a0);
        acc8(acc, snorm[k + 1], a1);
        acc8(acc, snorm[k + 2], a2);
        acc8(acc, snorm[k + 3], a3);
    }
    for (; k < end; ++k) acc8(acc, snorm[k], Mv[(size_t)srcrow[k] * 64 + t]);
    if (writeM) {
        uint4 st;
        st.x = pack2(acc[0], acc[1]); st.y = pack2(acc[2], acc[3]);
        st.z = pack2(acc[4], acc[5]); st.w = pack2(acc[6], acc[7]);
        ((uint4*)Mout)[(size_t)n * 64 + t] = st;
    }
    int h = t >> 3, ii = t & 7;
    epilogue64(acc, Q, hopwise[hopidx], n, h, ii, out);
}

extern "C" void kernel_launch(void* const* d_in, const int* in_sizes, int n_in,
                              void* d_out, int out_size, void* d_ws, size_t ws_size,
                              hipStream_t stream) {
    const float* x       = (const float*)d_in[0];
    const int*   ei      = (const int*)d_in[1];
    const float* ef      = (const float*)d_in[2];
    const float* ew      = (const float*)d_in[3];
    const float* Wq      = (const float*)d_in[4];
    const float* bq      = (const float*)d_in[5];
    const float* Wk      = (const float*)d_in[6];
    const float* bk      = (const float*)d_in[7];
    const float* Wv      = (const float*)d_in[8];
    const float* bv      = (const float*)d_in[9];
    const float* hopwise = (const float*)d_in[10];
    float* out = (float*)d_out;

    const int n = in_sizes[0] / HIDC;   // 10000
    const int e = in_sizes[1] / 2;      // 160000
    const int* row = ei;
    const int* col = ei + e;

    char* base = (char*)d_ws;
    size_t off = 0;
    auto alloc = [&](size_t bytes) -> void* {
        void* p = base + off;
        off = (off + bytes + 255) & ~(size_t)255;
        return p;
    };
    int*            deg     = (int*)           alloc((size_t)n * 4);
    int*            cursor  = (int*)           alloc((size_t)n * 4);
    int*            rowbeg  = (int*)           alloc((size_t)n * 4);
    int*            counter = (int*)           alloc(256);
    int*            srcrow  = (int*)           alloc((size_t)e * 4);
    float*          snorm   = (float*)         alloc((size_t)e * 4);
    unsigned short* kjv     = (unsigned short*)alloc((size_t)e * 128 * 2);
    float*          Q       = (float*)         alloc((size_t)n * HIDC * 4);
    float*          K       = (float*)         alloc((size_t)n * HIDC * 4);
    float*          V       = (float*)         alloc((size_t)n * HIDC * 4);
    unsigned short* M0      = (unsigned short*)alloc((size_t)n * MELEMS * 2);
    unsigned short* M1      = (unsigned short*)alloc((size_t)n * MELEMS * 2);
    (void)ws_size;

    // 4 nodes/thread-column: (n/4) waves of 64
    int qthreads = ((n + 3) / 4) * 64;
    int qb = (qthreads + 255) / 256;
    qkv_kernel<<<qb, 256, 0, stream>>>(x, Wq, bq, Wk, bk, Wv, bv, hopwise,
                                       Q, K, V, out, deg, counter, n);

    int eb = (e + 255) / 256;
    deg_kernel<<<eb, 256, 0, stream>>>(col, deg, e);

    int bb = (n + 1023) / 1024;
    base_kernel<<<bb, 1024, 0, stream>>>(deg, counter, rowbeg, cursor, n);

    int sb = ((e * 16) + 255) / 256;
    stage_kernel<<<sb, 256, 0, stream>>>(row, col, ew, deg, cursor,
                                         srcrow, snorm, K, V, ef, kjv, e);

    int nb = (n + 3) / 4;
    hop0_kernel<<<nb, 256, 0, stream>>>(rowbeg, deg, snorm, kjv, Q, hopwise, M0, out, n);
    hopk_kernel<<<nb, 256, 0, stream>>>(rowbeg, deg, srcrow, snorm, M0, Q, hopwise, 2, M1, 1, out, n);
    hopk_kernel<<<nb, 256, 0, stream>>>(rowbeg, deg, srcrow, snorm, M1, Q, hopwise, 3, M0, 0, out, n);
}

// Round 11
// 122.367 us; speedup vs baseline: 1.1578x; 1.0426x over previous
//
#include <hip/hip_runtime.h>
#include <hip/hip_bf16.h>

// MSTAGNN: N=10000, E=160000, HID=64, HEADS=8, D=8, KHOPS=3.
// R11: V removed from the staged edge row. stage writes only
// kjn[pos] = norm * relu(K[row]+ef)  (64 bf16 = 128B, norm pre-folded);
// hop0 streams kjn sequentially and gathers V from a bf16 table Vb
// (1.28MB, L2-resident, 8-thread-broadcast uint4 reads). Kills the ~16x
// per-edge duplication of V rows (41MB of HBM traffic). M propagated as
// bf16 rows, one wave/node, f32 accum. Parallel CSR base alloc. No memsets.
// K-propagation in the reference is dead code (never read after hop 0).

#define HIDC 64
#define MELEMS 512  // HEADS * D * D

__device__ __forceinline__ unsigned bf16rne(float x) {
    unsigned u = __float_as_uint(x);
    return (u + 0x7FFFu + ((u >> 16) & 1u)) >> 16;
}
__device__ __forceinline__ unsigned pack2(float lo, float hi) {
    return bf16rne(lo) | (bf16rne(hi) << 16);
}
__device__ __forceinline__ float bfval(unsigned short v) {
    return __uint_as_float((unsigned)v << 16);
}
__device__ __forceinline__ void acc8(float* acc, float s, uint4 a) {
    acc[0] = fmaf(s, __uint_as_float(a.x << 16), acc[0]);
    acc[1] = fmaf(s, __uint_as_float(a.x & 0xFFFF0000u), acc[1]);
    acc[2] = fmaf(s, __uint_as_float(a.y << 16), acc[2]);
    acc[3] = fmaf(s, __uint_as_float(a.y & 0xFFFF0000u), acc[3]);
    acc[4] = fmaf(s, __uint_as_float(a.z << 16), acc[4]);
    acc[5] = fmaf(s, __uint_as_float(a.z & 0xFFFF0000u), acc[5]);
    acc[6] = fmaf(s, __uint_as_float(a.w << 16), acc[6]);
    acc[7] = fmaf(s, __uint_as_float(a.w & 0xFFFF0000u), acc[7]);
}

// Q,K = x@W + b (relu on Q); Vb = bf16(x@Wv+bv); out = hopwise[0]*V (full
// overwrite -> replay safe). 4 nodes/thread: W column read once per 4 nodes.
// Side jobs: zero deg[] and the CSR base counter.
__global__ __launch_bounds__(256) void qkv_kernel(
    const float* __restrict__ x,
    const float* __restrict__ Wq, const float* __restrict__ bq,
    const float* __restrict__ Wk, const float* __restrict__ bk,
    const float* __restrict__ Wv, const float* __restrict__ bv,
    const float* __restrict__ hopwise,
    float* __restrict__ Q, float* __restrict__ K,
    unsigned short* __restrict__ Vb,
    float* __restrict__ out, int* __restrict__ deg,
    int* __restrict__ counter, int n) {
    int gid = blockIdx.x * blockDim.x + threadIdx.x;
    if (gid < n) deg[gid] = 0;
    if (gid == 0) *counter = 0;
    int c = gid & 63;
    int nb = (gid >> 6) * 4;
    if (nb >= n) return;
    int mcnt = min(4, n - nb);
    float aq[4], ak[4], av[4];
    #pragma unroll
    for (int m = 0; m < 4; ++m) { aq[m] = bq[c]; ak[m] = bk[c]; av[m] = bv[c]; }
    const float4* x4 = (const float4*)x;
    for (int k4 = 0; k4 < 16; ++k4) {
        float4 xv[4];
        #pragma unroll
        for (int m = 0; m < 4; ++m)
            xv[m] = x4[(size_t)(nb + (m < mcnt ? m : 0)) * 16 + k4];
        #pragma unroll
        for (int kk = 0; kk < 4; ++kk) {
            int k = k4 * 4 + kk;
            float wq = Wq[k * HIDC + c], wk = Wk[k * HIDC + c], wv = Wv[k * HIDC + c];
            #pragma unroll
            for (int m = 0; m < 4; ++m) {
                float xvk = (kk == 0) ? xv[m].x : (kk == 1) ? xv[m].y
                          : (kk == 2) ? xv[m].z : xv[m].w;
                aq[m] = fmaf(xvk, wq, aq[m]);
                ak[m] = fmaf(xvk, wk, ak[m]);
                av[m] = fmaf(xvk, wv, av[m]);
            }
        }
    }
    #pragma unroll
    for (int m = 0; m < 4; ++m) {
        if (m < mcnt) {
            size_t idx = (size_t)(nb + m) * HIDC + c;
            Q[idx] = fmaxf(aq[m], 0.f);
            K[idx] = ak[m];
            Vb[idx] = (unsigned short)bf16rne(av[m]);
            out[idx] = hopwise[0] * av[m];
        }
    }
}

__global__ void deg_kernel(const int* __restrict__ col, int* __restrict__ deg, int e) {
    int i = blockIdx.x * blockDim.x + threadIdx.x;
    if (i < e) atomicAdd(&deg[col[i]], 1);
}

// parallel CSR base allocation: per-1024-node block scan + atomic block base.
// rowbeg[i] = cursor[i] = global slot base for node i (NOT globally monotone;
// hop kernels use end = rowbeg[n] + deg[n]).
__global__ __launch_bounds__(1024) void base_kernel(const int* __restrict__ deg,
                                                    int* __restrict__ counter,
                                                    int* __restrict__ rowbeg,
                                                    int* __restrict__ cursor, int n) {
    __shared__ int wsum[16];
    __shared__ int blockbase;
    int i = blockIdx.x * 1024 + threadIdx.x;
    int lane = threadIdx.x & 63, w = threadIdx.x >> 6;
    int v = (i < n) ? deg[i] : 0;
    int s = v;
    #pragma unroll
    for (int off = 1; off < 64; off <<= 1) {
        int t = __shfl_up(s, off);
        if (lane >= off) s += t;
    }
    if (lane == 63) wsum[w] = s;
    __syncthreads();
    if (threadIdx.x == 0) {
        int acc = 0;
        #pragma unroll
        for (int w2 = 0; w2 < 16; ++w2) { int t = wsum[w2]; wsum[w2] = acc; acc += t; }
        blockbase = atomicAdd(counter, acc);
    }
    __syncthreads();
    int excl = blockbase + wsum[w] + s - v;
    if (i < n) {
        rowbeg[i] = excl;
        cursor[i] = excl;
    }
}

// fused pos+stage: 16 threads/edge. Leader (c4==0) computes norm + CSR slot
// (atomic), writes srcrow/snorm, broadcasts {r,pos,nv}; all 16 lanes stage
// kjn[pos] = nv * relu(K[r]+ef[i]) as 64 bf16 (128B row, norm pre-folded).
// ef read sequential/coalesced; K gathers L2-resident.
__global__ __launch_bounds__(256) void stage_kernel(
    const int* __restrict__ row, const int* __restrict__ col,
    const float* __restrict__ ew, const int* __restrict__ deg,
    int* __restrict__ cursor, int* __restrict__ srcrow,
    float* __restrict__ snorm,
    const float* __restrict__ K, const float* __restrict__ ef,
    unsigned short* __restrict__ kjn, int e) {
    int gtid = blockIdx.x * blockDim.x + threadIdx.x;
    int i = gtid >> 4;
    if (i >= e) return;
    int c4 = gtid & 15;
    int lane = threadIdx.x & 63;
    int lb = lane & 48;  // leader lane of this 16-thread group
    int r = 0, pos = 0;
    float nv = 0.f;
    if (c4 == 0) {
        r = row[i];
        int cc = col[i];
        int dr = deg[r], dc = deg[cc];
        nv = ew[i];
        nv *= (dr > 0) ? rsqrtf((float)dr) : 0.f;
        nv *= (dc > 0) ? rsqrtf((float)dc) : 0.f;
        pos = atomicAdd(&cursor[cc], 1);
        srcrow[pos] = r;
        snorm[pos] = nv;
    }
    r = __shfl(r, lb);
    pos = __shfl(pos, lb);
    nv = __shfl(nv, lb);
    const float4* efv = (const float4*)ef;
    const float4* Kv = (const float4*)K;
    float4 f = efv[(size_t)i * 16 + c4];
    float4 kk = Kv[(size_t)r * 16 + c4];
    uint2 kjp;
    kjp.x = pack2(nv * fmaxf(kk.x + f.x, 0.f), nv * fmaxf(kk.y + f.y, 0.f));
    kjp.y = pack2(nv * fmaxf(kk.z + f.z, 0.f), nv * fmaxf(kk.w + f.w, 0.f));
    ((uint2*)(kjn + (size_t)pos * 64))[c4] = kjp;
}

// epilogue (64 threads/node, t = h*8+ii owns M[h][ii][0..7]):
// H = Q.M (reduce ii via xor 1/2/4), clamp-norm (j-reduce in-thread)
__device__ __forceinline__ void epilogue64(const float* acc, const float* __restrict__ Q,
                                           float hw, int n, int h, int ii,
                                           float* __restrict__ out) {
    float q = Q[n * HIDC + h * 8 + ii];
    float p[8];
    #pragma unroll
    for (int j = 0; j < 8; ++j) p[j] = q * acc[j];
    #pragma unroll
    for (int off = 1; off < 8; off <<= 1) {
        #pragma unroll
        for (int j = 0; j < 8; ++j) p[j] += __shfl_xor(p[j], off);
    }
    float ssq = 0.f;
    #pragma unroll
    for (int j = 0; j < 8; ++j) ssq = fmaf(p[j], p[j], ssq);
    float nr = sqrtf(ssq * 0.125f);
    float sc = (nr > 1.f) ? (hw / nr) : hw;
    if (ii == 0) {
        float4* o = (float4*)(out + (size_t)n * HIDC + h * 8);
        float4 c0 = o[0], c1 = o[1];
        c0.x = fmaf(p[0], sc, c0.x); c0.y = fmaf(p[1], sc, c0.y);
        c0.z = fmaf(p[2], sc, c0.z); c0.w = fmaf(p[3], sc, c0.w);
        c1.x = fmaf(p[4], sc, c1.x); c1.y = fmaf(p[5], sc, c1.y);
        c1.z = fmaf(p[6], sc, c1.z); c1.w = fmaf(p[7], sc, c1.w);
        o[0] = c0; o[1] = c1;
    }
}

// hop 0: one wave per node; kjn streamed sequentially (1 ushort/edge/thread,
// norm pre-folded), V gathered from the 1.28MB L2-resident bf16 table
// (8 threads broadcast-share each uint4). Unroll 4 for MLP.
__global__ __launch_bounds__(256) void hop0_kernel(
    const int* __restrict__ rowbeg, const int* __restrict__ deg,
    const int* __restrict__ srcrow, const unsigned short* __restrict__ kjn,
    const unsigned short* __restrict__ Vb,
    const float* __restrict__ Q, const float* __restrict__ hopwise,
    unsigned short* __restrict__ M0, float* __restrict__ out, int nn) {
    int n = blockIdx.x * 4 + (threadIdx.x >> 6);
    if (n >= nn) return;
    int t = threadIdx.x & 63;
    int h = t >> 3, ii = t & 7;
    int beg = rowbeg[n], end = beg + deg[n];
    float acc[8] = {0, 0, 0, 0, 0, 0, 0, 0};
    int k = beg;
    for (; k + 4 <= end; k += 4) {
        int j0 = srcrow[k],     j1 = srcrow[k + 1];
        int j2 = srcrow[k + 2], j3 = srcrow[k + 3];
        float s0 = bfval(kjn[(size_t)(k)     * 64 + t]);
        float s1 = bfval(kjn[(size_t)(k + 1) * 64 + t]);
        float s2 = bfval(kjn[(size_t)(k + 2) * 64 + t]);
        float s3 = bfval(kjn[(size_t)(k + 3) * 64 + t]);
        uint4 v0 = *(const uint4*)(Vb + (size_t)j0 * 64 + h * 8);
        uint4 v1 = *(const uint4*)(Vb + (size_t)j1 * 64 + h * 8);
        uint4 v2 = *(const uint4*)(Vb + (size_t)j2 * 64 + h * 8);
        uint4 v3 = *(const uint4*)(Vb + (size_t)j3 * 64 + h * 8);
        acc8(acc, s0, v0);
        acc8(acc, s1, v1);
        acc8(acc, s2, v2);
        acc8(acc, s3, v3);
    }
    for (; k < end; ++k) {
        float s = bfval(kjn[(size_t)k * 64 + t]);
        uint4 v = *(const uint4*)(Vb + (size_t)srcrow[k] * 64 + h * 8);
        acc8(acc, s, v);
    }
    uint4 st;
    st.x = pack2(acc[0], acc[1]); st.y = pack2(acc[2], acc[3]);
    st.z = pack2(acc[4], acc[5]); st.w = pack2(acc[6], acc[7]);
    ((uint4*)M0)[(size_t)n * 64 + t] = st;
    epilogue64(acc, Q, hopwise[1], n, h, ii, out);
}

// hop k>=1: Mout[n] = sum_e norm * Min[row[e]]; one wave per node, bf16 rows,
// unroll 8 for MLP on the random row gathers.
__global__ __launch_bounds__(256) void hopk_kernel(
    const int* __restrict__ rowbeg, const int* __restrict__ deg,
    const int* __restrict__ srcrow, const float* __restrict__ snorm,
    const unsigned short* __restrict__ Min, const float* __restrict__ Q,
    const float* __restrict__ hopwise, int hopidx,
    unsigned short* __restrict__ Mout, int writeM, float* __restrict__ out, int nn) {
    int n = blockIdx.x * 4 + (threadIdx.x >> 6);
    if (n >= nn) return;
    int t = threadIdx.x & 63;
    int beg = rowbeg[n], end = beg + deg[n];
    float acc[8] = {0, 0, 0, 0, 0, 0, 0, 0};
    const uint4* Mv = (const uint4*)Min;  // row j at Mv[j*64 + t]
    int k = beg;
    for (; k + 8 <= end; k += 8) {
        int j0 = srcrow[k],     j1 = srcrow[k + 1], j2 = srcrow[k + 2], j3 = srcrow[k + 3];
        int j4 = srcrow[k + 4], j5 = srcrow[k + 5], j6 = srcrow[k + 6], j7 = srcrow[k + 7];
        uint4 a0 = Mv[(size_t)j0 * 64 + t];
        uint4 a1 = Mv[(size_t)j1 * 64 + t];
        uint4 a2 = Mv[(size_t)j2 * 64 + t];
        uint4 a3 = Mv[(size_t)j3 * 64 + t];
        uint4 a4 = Mv[(size_t)j4 * 64 + t];
        uint4 a5 = Mv[(size_t)j5 * 64 + t];
        uint4 a6 = Mv[(size_t)j6 * 64 + t];
        uint4 a7 = Mv[(size_t)j7 * 64 + t];
        acc8(acc, snorm[k],     a0);
        acc8(acc, snorm[k + 1], a1);
        acc8(acc, snorm[k + 2], a2);
        acc8(acc, snorm[k + 3], a3);
        acc8(acc, snorm[k + 4], a4);
        acc8(acc, snorm[k + 5], a5);
        acc8(acc, snorm[k + 6], a6);
        acc8(acc, snorm[k + 7], a7);
    }
    for (; k + 4 <= end; k += 4) {
        int j0 = srcrow[k], j1 = srcrow[k + 1], j2 = srcrow[k + 2], j3 = srcrow[k + 3];
        uint4 a0 = Mv[(size_t)j0 * 64 + t];
        uint4 a1 = Mv[(size_t)j1 * 64 + t];
        uint4 a2 = Mv[(size_t)j2 * 64 + t];
        uint4 a3 = Mv[(size_t)j3 * 64 + t];
        acc8(acc, snorm[k],     a0);
        acc8(acc, snorm[k + 1], a1);
        acc8(acc, snorm[k + 2], a2);
        acc8(acc, snorm[k + 3], a3);
    }
    for (; k < end; ++k) acc8(acc, snorm[k], Mv[(size_t)srcrow[k] * 64 + t]);
    if (writeM) {
        uint4 st;
        st.x = pack2(acc[0], acc[1]); st.y = pack2(acc[2], acc[3]);
        st.z = pack2(acc[4], acc[5]); st.w = pack2(acc[6], acc[7]);
        ((uint4*)Mout)[(size_t)n * 64 + t] = st;
    }
    int h = t >> 3, ii = t & 7;
    epilogue64(acc, Q, hopwise[hopidx], n, h, ii, out);
}

extern "C" void kernel_launch(void* const* d_in, const int* in_sizes, int n_in,
                              void* d_out, int out_size, void* d_ws, size_t ws_size,
                              hipStream_t stream) {
    const float* x       = (const float*)d_in[0];
    const int*   ei      = (const int*)d_in[1];
    const float* ef      = (const float*)d_in[2];
    const float* ew      = (const float*)d_in[3];
    const float* Wq      = (const float*)d_in[4];
    const float* bq      = (const float*)d_in[5];
    const float* Wk      = (const float*)d_in[6];
    const float* bk      = (const float*)d_in[7];
    const float* Wv      = (const float*)d_in[8];
    const float* bv      = (const float*)d_in[9];
    const float* hopwise = (const float*)d_in[10];
    float* out = (float*)d_out;

    const int n = in_sizes[0] / HIDC;   // 10000
    const int e = in_sizes[1] / 2;      // 160000
    const int* row = ei;
    const int* col = ei + e;

    char* base = (char*)d_ws;
    size_t off = 0;
    auto alloc = [&](size_t bytes) -> void* {
        void* p = base + off;
        off = (off + bytes + 255) & ~(size_t)255;
        return p;
    };
    int*            deg     = (int*)           alloc((size_t)n * 4);
    int*            cursor  = (int*)           alloc((size_t)n * 4);
    int*            rowbeg  = (int*)           alloc((size_t)n * 4);
    int*            counter = (int*)           alloc(256);
    int*            srcrow  = (int*)           alloc((size_t)e * 4);
    float*          snorm   = (float*)         alloc((size_t)e * 4);
    unsigned short* kjn     = (unsigned short*)alloc((size_t)e * HIDC * 2);
    float*          Q       = (float*)         alloc((size_t)n * HIDC * 4);
    float*          K       = (float*)         alloc((size_t)n * HIDC * 4);
    unsigned short* Vb      = (unsigned short*)alloc((size_t)n * HIDC * 2);
    unsigned short* M0      = (unsigned short*)alloc((size_t)n * MELEMS * 2);
    unsigned short* M1      = (unsigned short*)alloc((size_t)n * MELEMS * 2);
    (void)ws_size;

    // 4 nodes/thread-column: (n/4) waves of 64
    int qthreads = ((n + 3) / 4) * 64;
    int qb = (qthreads + 255) / 256;
    qkv_kernel<<<qb, 256, 0, stream>>>(x, Wq, bq, Wk, bk, Wv, bv, hopwise,
                                       Q, K, Vb, out, deg, counter, n);

    int eb = (e + 255) / 256;
    deg_kernel<<<eb, 256, 0, stream>>>(col, deg, e);

    int bb = (n + 1023) / 1024;
    base_kernel<<<bb, 1024, 0, stream>>>(deg, counter, rowbeg, cursor, n);

    int sb = ((e * 16) + 255) / 256;
    stage_kernel<<<sb, 256, 0, stream>>>(row, col, ew, deg, cursor,
                                         srcrow, snorm, K, ef, kjn, e);

    int nb = (n + 3) / 4;
    hop0_kernel<<<nb, 256, 0, stream>>>(rowbeg, deg, srcrow, kjn, Vb, Q,
                                        hopwise, M0, out, n);
    hopk_kernel<<<nb, 256, 0, stream>>>(rowbeg, deg, srcrow, snorm, M0, Q, hopwise, 2, M1, 1, out, n);
    hopk_kernel<<<nb, 256, 0, stream>>>(rowbeg, deg, srcrow, snorm, M1, Q, hopwise, 3, M0, 0, out, n);
}